// Round 3
// baseline (477.214 us; speedup 1.0000x reference)
//
#include <hip/hip_runtime.h>
#include <math.h>

#define NBF 4104      // B*F = 8*513
#define XT_FLOATS 16809984   // 8*513*8*512

// Module-scope device scratch (static allocation; no reliance on d_ws size).
// Fully overwritten every call before being read -> deterministic.
__device__ float d_partials[NBF];
__device__ float d_scales[8];

__global__ __launch_bounds__(256) void iss_main(
    const float* __restrict__ g_r,
    const float* __restrict__ g_xre,
    const float* __restrict__ g_xim,
    const float* __restrict__ g_Qre,
    const float* __restrict__ g_Qim,
    float* __restrict__ g_out,
    const int qmode,        // 2 = interleaved re,im pairs; 1 = real part only
    const int xt_off)       // float offset where the xt region begins
{
    __shared__ float  s_r [8][512];
    __shared__ float  s_xr[8][512];
    __shared__ float  s_xi[8][512];
    __shared__ float2 s_V [8][8][9];   // padded to break bank conflicts in phase B
    __shared__ float2 s_Q [8][8];
    __shared__ float2 s_Vq[8][8];
    __shared__ float  s_p [8][8];
    __shared__ float2 s_qold[8];
    __shared__ float2 s_vv[8];
    __shared__ float  s_part[4];

    const int tid = threadIdx.x;
    const int bf  = blockIdx.x;
    const size_t base = (size_t)bf * 4096;

    // ---- load r (with max(.,1e-3)), x_re, x_im, Q into LDS (float4, coalesced) ----
    {
        const float4* r4  = (const float4*)(g_r   + base);
        const float4* xr4 = (const float4*)(g_xre + base);
        const float4* xi4 = (const float4*)(g_xim + base);
        float4* sr  = (float4*)&s_r[0][0];
        float4* sxr = (float4*)&s_xr[0][0];
        float4* sxi = (float4*)&s_xi[0][0];
        #pragma unroll
        for (int i = 0; i < 4; ++i) {
            const int idx = tid + (i << 8);
            float4 rv = r4[idx];
            rv.x = fmaxf(rv.x, 1e-3f); rv.y = fmaxf(rv.y, 1e-3f);
            rv.z = fmaxf(rv.z, 1e-3f); rv.w = fmaxf(rv.w, 1e-3f);
            sr[idx]  = rv;
            sxr[idx] = xr4[idx];
            sxi[idx] = xi4[idx];
        }
        if (tid < 64)
            s_Q[tid>>3][tid&7] = make_float2(g_Qre[(size_t)bf*64 + tid],
                                             g_Qim[(size_t)bf*64 + tid]);
    }
    __syncthreads();

    // ---- phase A: V[k][m][n] = (1/T) sum_t max(r,1e-3) x_m conj(x_n), Hermitian ----
    const int k  = tid >> 5;   // 0..7, each k owned by 32 threads (one half-wave)
    const int tc = tid & 31;
    float accd[8] = {0,0,0,0,0,0,0,0};
    float accr[28], acci[28];
    #pragma unroll
    for (int p = 0; p < 28; ++p) { accr[p] = 0.f; acci[p] = 0.f; }

    for (int it = 0; it < 16; ++it) {
        const int t = tc + (it << 5);
        const float rw = s_r[k][t];
        float xr[8], xi[8];
        #pragma unroll
        for (int m = 0; m < 8; ++m) { xr[m] = s_xr[m][t]; xi[m] = s_xi[m][t]; }
        int p = 0;
        #pragma unroll
        for (int m = 0; m < 8; ++m) {
            const float yr = rw * xr[m], yi = rw * xi[m];
            accd[m] += yr*xr[m] + yi*xi[m];
            #pragma unroll
            for (int n = m+1; n < 8; ++n, ++p) {
                accr[p] += yr*xr[n] + yi*xi[n];
                acci[p] += yi*xr[n] - yr*xi[n];
            }
        }
    }

    // reduce over the 32 threads sharing k (xor offsets <=16 stay inside each half-wave)
    #pragma unroll
    for (int m = 0; m < 8; ++m) {
        #pragma unroll
        for (int off = 16; off >= 1; off >>= 1) accd[m] += __shfl_xor(accd[m], off, 64);
    }
    #pragma unroll
    for (int p = 0; p < 28; ++p) {
        #pragma unroll
        for (int off = 16; off >= 1; off >>= 1) accr[p] += __shfl_xor(accr[p], off, 64);
        #pragma unroll
        for (int off = 16; off >= 1; off >>= 1) acci[p] += __shfl_xor(acci[p], off, 64);
    }

    if (tc == 0) {
        const float invT = 1.0f / 512.0f;
        float d[8]; float tr = 0.f;
        #pragma unroll
        for (int m = 0; m < 8; ++m) { d[m] = accd[m]*invT; tr += d[m]; }
        const float e = fmaxf(tr, 1.0f) * 1e-6f;
        #pragma unroll
        for (int m = 0; m < 8; ++m) s_V[k][m][m] = make_float2(d[m] + e, 0.f);
        int p = 0;
        #pragma unroll
        for (int m = 0; m < 8; ++m) {
            #pragma unroll
            for (int n = m+1; n < 8; ++n, ++p) {
                const float vr = accr[p]*invT, vi = acci[p]*invT;
                s_V[k][m][n] = make_float2(vr,  vi);
                s_V[k][n][m] = make_float2(vr, -vi);
            }
        }
    }
    __syncthreads();

    // ---- phase B: 2 iterations x 8 sequential row updates ----
    for (int iter = 0; iter < 2; ++iter) {
        for (int kk = 0; kk < 8; ++kk) {
            if (tid < 64) {
                const int kp = tid >> 3, m = tid & 7;
                if (tid < 8) s_qold[tid] = s_Q[kk][tid];   // snapshot old row kk
                float vqr = 0.f, vqi = 0.f;
                #pragma unroll
                for (int n = 0; n < 8; ++n) {
                    const float2 V = s_V[kp][m][n];
                    const float2 q = s_Q[kk][n];
                    vqr += V.x*q.x + V.y*q.y;   // V * conj(q)
                    vqi += V.y*q.x - V.x*q.y;
                }
                s_Vq[kp][m] = make_float2(vqr, vqi);
                const float2 qm = s_Q[kk][m];
                s_p[kp][m] = qm.x*vqr - qm.y*vqi;    // Re(q_m * Vq_m)
            }
            __syncthreads();
            if (tid < 8) {
                const int kp = tid;
                float qvq = 0.f;
                #pragma unroll
                for (int m = 0; m < 8; ++m) qvq += s_p[kp][m];
                qvq = fmaxf(qvq, 1e-6f);
                float vr, vi;
                if (kp == kk) { vr = 1.0f - rsqrtf(qvq); vi = 0.f; }
                else {
                    float ar = 0.f, ai = 0.f;
                    #pragma unroll
                    for (int m = 0; m < 8; ++m) {
                        const float2 Qm = s_Q[kp][m];
                        const float2 Vq = s_Vq[kp][m];
                        ar += Qm.x*Vq.x - Qm.y*Vq.y;   // Q * Vq (no conj)
                        ai += Qm.x*Vq.y + Qm.y*Vq.x;
                    }
                    const float inv = 1.0f / qvq;
                    vr = ar*inv; vi = ai*inv;
                }
                s_vv[kp] = make_float2(vr, vi);
            }
            __syncthreads();
            if (tid < 64) {
                const int kp = tid >> 3, m = tid & 7;
                const float2 v = s_vv[kp], q = s_qold[m];
                float2 Qv = s_Q[kp][m];
                Qv.x -= v.x*q.x - v.y*q.y;
                Qv.y -= v.x*q.y + v.y*q.x;
                s_Q[kp][m] = Qv;
            }
            __syncthreads();
        }
    }

    // ---- phase C: xt = |Q x|^2 (unnormalized), block partial sum, write Q ----
    float lsum = 0.f;
    float* out_xt = g_out + xt_off;
    #pragma unroll
    for (int j = 0; j < 16; ++j) {
        const int idx = tid + (j << 8);
        const int m = idx >> 9, t = idx & 511;
        float qxr = 0.f, qxi = 0.f;
        #pragma unroll
        for (int n = 0; n < 8; ++n) {
            const float2 Q = s_Q[m][n];
            const float xr = s_xr[n][t], xi = s_xi[n][t];
            qxr += Q.x*xr - Q.y*xi;
            qxi += Q.x*xi + Q.y*xr;
        }
        const float pw = qxr*qxr + qxi*qxi;
        out_xt[base + idx] = pw;
        lsum += pw;
    }
    #pragma unroll
    for (int off = 32; off >= 1; off >>= 1) lsum += __shfl_xor(lsum, off, 64);
    if ((tid & 63) == 0) s_part[tid >> 6] = lsum;
    __syncthreads();
    if (tid == 0) d_partials[bf] = s_part[0] + s_part[1] + s_part[2] + s_part[3];
    if (tid < 64) {
        const float2 Qv = s_Q[tid>>3][tid&7];
        if (qmode == 2) {
            g_out[(size_t)bf*128 + tid*2]     = Qv.x;
            g_out[(size_t)bf*128 + tid*2 + 1] = Qv.y;
        } else {
            g_out[(size_t)bf*64 + tid] = Qv.x;   // real-part-only layout hypothesis
        }
    }
}

__global__ __launch_bounds__(256) void iss_scale()
{
    const int b = blockIdx.x, tid = threadIdx.x;
    __shared__ float sp[4];
    float s = 0.f;
    for (int i = tid; i < 513; i += 256) s += d_partials[b*513 + i];
    #pragma unroll
    for (int off = 32; off >= 1; off >>= 1) s += __shfl_xor(s, off, 64);
    if ((tid & 63) == 0) sp[tid >> 6] = s;
    __syncthreads();
    if (tid == 0) d_scales[b] = (sp[0]+sp[1]+sp[2]+sp[3]) / (513.0f * 8.0f * 512.0f);
}

__global__ __launch_bounds__(256) void iss_norm(
    float* __restrict__ g_out,
    const int nq4,     // Q region in float4s  (= xt_off/4)
    const int qb4,     // float4s per batch in Q region
    const int nt4)     // total float4s (= out_size/4)
{
    float4* o4 = (float4*)g_out;
    for (int i = blockIdx.x*256 + threadIdx.x; i < nt4; i += gridDim.x*256) {
        float s;
        if (i < nq4) {
            const int b = i / qb4;
            s = rsqrtf(fmaxf(d_scales[b], 1e-6f));
        } else {
            const int j = i - nq4;
            const int b = j / 525312;          // xt float4s per batch
            s = 1.0f / d_scales[b];
        }
        float4 v = o4[i];
        v.x *= s; v.y *= s; v.z *= s; v.w *= s;
        o4[i] = v;
    }
}

extern "C" void kernel_launch(void* const* d_in, const int* in_sizes, int n_in,
                              void* d_out, int out_size, void* d_ws, size_t ws_size,
                              hipStream_t stream) {
    const float* r   = (const float*)d_in[0];
    const float* xre = (const float*)d_in[1];
    const float* xim = (const float*)d_in[2];
    const float* Qre = (const float*)d_in[3];
    const float* Qim = (const float*)d_in[4];
    float* out = (float*)d_out;

    // Derive the Q-region layout from the actual buffer size instead of assuming it.
    // xt is unambiguously XT_FLOATS float32 elements; whatever remains belongs to Q.
    const int q_floats = out_size - XT_FLOATS;
    const int qmode  = (q_floats >= 525312) ? 2 : 1;  // 2: interleaved re,im; 1: real only
    const int xt_off = (qmode == 2) ? 525312 : 262656;
    const int nq4 = xt_off / 4;
    const int qb4 = xt_off / (4 * 8);                  // per-batch float4s in Q region
    const int nt4 = nq4 + XT_FLOATS / 4;

    iss_main <<<NBF, 256, 0, stream>>>(r, xre, xim, Qre, Qim, out, qmode, xt_off);
    iss_scale<<<8,   256, 0, stream>>>();
    iss_norm <<<4096,256, 0, stream>>>(out, nq4, qb4, nt4);
}